// Round 1
// baseline (168.651 us; speedup 1.0000x reference)
//
#include <hip/hip_runtime.h>
#include <math.h>

#define BS 2
#define QLEN 64
#define KLEN 64
#define NH 8
#define DKV 64
#define INNER 512
#define VOCAB 4096
#define CHUNKV 64
#define RS 130               // Cv stride (doubles), even -> 16B-aligned b128 reads
#define BUFD (CHUNKV * RS)   // 8320 doubles per buffer

typedef double vdbl4 __attribute__((ext_vector_type(4)));
typedef double vdbl2 __attribute__((ext_vector_type(2)));

// ---------------- workspace layout (bytes) ----------------
// qp    : [BS][64][INNER] double  @ 0        (512 KB)
// kp    : [BS][64][INNER] double  @ 512 KB   (512 KB)
// dnt   : [DKV][VOCAB]    double  @ 1 MB     (2 MB)   l2-normalized dict, transposed
// E     : [VOCAB][DKV]    float   @ 3 MB     (1 MB)   LN(dict) @ vq_o_w
// bestf : [16][64][64]    u64     @ 4 MB     (512 KB) atomicMax'd packed (val | 4095-v code)

// ======== prep: proj GEMM (blocks 0..1023) + dict (blocks 1024..2047) — r12 exact ========
__global__ __launch_bounds__(256) void k_prep(
    const float* __restrict__ q_in, const float* __restrict__ k_in,
    const float* __restrict__ qpe, const float* __restrict__ kpe,
    const float* __restrict__ wi,
    const float* __restrict__ vq, const float* __restrict__ g,
    const float* __restrict__ bta, const float* __restrict__ ow,
    double* __restrict__ qp, double* __restrict__ kp,
    double* __restrict__ dnt, float* __restrict__ E,
    unsigned long long* __restrict__ bestf)
{
    __shared__ double S[1600];           // proj: xs[1024]+red[512]; dict: Lsh[256]+Dsh[320]
    __shared__ float Osh[4096];          // dict: ow cache
    int bid = blockIdx.x;
    int t = threadIdx.x;

    if (bid < 1024) {
        int side = bid >> 9;
        int b    = (bid >> 8) & 1;
        int rp   = (bid >> 3) & 31;
        int cb   = bid & 7;
        const float* xin = side ? k_in : q_in;
        const float* pin = side ? kpe : qpe;
        double* outp = side ? kp : qp;
        int wrow0 = side ? INNER : 0;
        int r0 = rp * 2;
        double* xs = S;                  // [2][512]
        double* red = S + 1024;          // [dh*2+rr][64]
        for (int i = t; i < 2 * INNER; i += 256) {
            int rr = i >> 9, dd = i & 511;
            int gidx = (b * 64 + r0 + rr) * INNER + dd;
            xs[rr * INNER + dd] = (double)xin[gidx] + (double)pin[gidx];
        }
        __syncthreads();
        int col = cb * 64 + (t & 63);
        int dh = t >> 6;
        double a0 = 0.0, a1 = 0.0;
        #pragma unroll 8
        for (int d = dh * 128; d < dh * 128 + 128; ++d) {
            double w = (double)wi[(size_t)(wrow0 + d) * INNER + col];
            a0 = fma(xs[d], w, a0);
            a1 = fma(xs[INNER + d], w, a1);
        }
        red[(dh * 2 + 0) * 64 + (t & 63)] = a0;
        red[(dh * 2 + 1) * 64 + (t & 63)] = a1;
        __syncthreads();
        if (t < 128) {
            int rr = t >> 6, c2 = t & 63;
            double s = (red[(0 * 2 + rr) * 64 + c2] + red[(1 * 2 + rr) * 64 + c2])
                     + (red[(2 * 2 + rr) * 64 + c2] + red[(3 * 2 + rr) * 64 + c2]);
            outp[(size_t)(b * 64 + r0 + rr) * INNER + cb * 64 + c2] = s;
        }
    } else {
        int db = bid - 1024;             // 0..1023, 4 vocab rows each (1 per wave)
        if (db < 256) bestf[db * 256 + t] = 0ull;
        double* Lsh = S;                 // [wave(4)][64] LN values
        double* Dsh = S + 256;           // [j(64)][5] dn staging (vloc = wave)
        int vb = db * 4;
        int wv = t >> 6, lane = t & 63;
        for (int i = t; i < 4096; i += 256) Osh[i] = ow[i];
        int v = vb + wv;
        double z = (double)vq[v * DKV + lane];
        double s2 = z * z, s1 = z;
        for (int m = 32; m >= 1; m >>= 1) { s2 += __shfl_xor(s2, m); s1 += __shfl_xor(s1, m); }
        Dsh[lane * 5 + wv] = z * (1.0 / sqrt(fmax(s2, 1e-12)));
        double mean = s1 * (1.0 / 64.0);
        double d0 = z - mean;
        double vv2 = d0 * d0;
        for (int m = 32; m >= 1; m >>= 1) vv2 += __shfl_xor(vv2, m);
        vv2 *= (1.0 / 64.0);
        Lsh[wv * 64 + lane] = d0 * (1.0 / sqrt(vv2 + 1e-6)) * (double)g[lane] + (double)bta[lane];
        __syncthreads();
        double c0 = 0.0, c1 = 0.0, c2 = 0.0, c3 = 0.0;
        #pragma unroll 4
        for (int gg = 0; gg < 16; ++gg) {
            int jj = gg * 4;
            c0 = fma(Lsh[wv * 64 + jj + 0], (double)Osh[(jj + 0) * 64 + lane], c0);
            c1 = fma(Lsh[wv * 64 + jj + 1], (double)Osh[(jj + 1) * 64 + lane], c1);
            c2 = fma(Lsh[wv * 64 + jj + 2], (double)Osh[(jj + 2) * 64 + lane], c2);
            c3 = fma(Lsh[wv * 64 + jj + 3], (double)Osh[(jj + 3) * 64 + lane], c3);
        }
        E[v * DKV + lane] = (float)((c0 + c1) + (c2 + c3));
        {
            int j = t >> 2, vloc = t & 3;
            dnt[(size_t)j * VOCAB + vb + vloc] = Dsh[j * 5 + vloc];
        }
    }
}

// ======== producer/consumer MFMA-f64 sim + scan — LDS-semaphore sync ========
// r12 pipeline; consumer rewritten to 8x4 register blocking:
//   each consumer thread owns an 8q x 4k tile (best[8][4], 64 VGPR) and reads
//   8 q + 4 k doubles (6 x b128) per v for 32 pair-updates (3 B/update vs 6).
//   4096 pairs = 128 tiles x 4 v-slices (16 v each per 64-chunk); a
//   transposed LDS tree-reduce collapses the 4 slices so global atomicMax
//   count stays 4096/block.
// LDS layout per v-row (RS=130 dbl): [0..63]=q (granule-swizzled:
//   p = 4*qi + ((r+qi)&3), 2-way-free reads), [64..127]=k (identity; natural
//   32B stride is already 2-way-free), [128..129] pad.
__global__ __launch_bounds__(1024, 4) void k_simscan(
    const double* __restrict__ qp, const double* __restrict__ kp,
    const double* __restrict__ dnt,
    unsigned long long* __restrict__ bestf)
{
    int bid = blockIdx.x;             // 256 = cg(16) x bh(16)
    int bh = bid & 15, cg = bid >> 4;
    int b = bh >> 3, h = bh & 7;
    int t = threadIdx.x;
    int w = t >> 6, l = t & 63;

    __shared__ double S[2 * BUFD];    // 133120 B -> 1 block/CU
    __shared__ int sem[9];            // [0..3]=prod_cnt, [4..7]=cons_cnt, [8]=red_cnt

    int asub = l >> 4;
    int lrow = l & 15;
    bool isprod = (w < 8);

    if (t < 9) sem[t] = 0;

    // ---- D-layout probes (verified calibration, rounds 6-15) ----
    int drow[4], dcol[4];
    {
        vdbl4 prow = (vdbl4){0.0, 0.0, 0.0, 0.0};
        vdbl4 pcol = (vdbl4){0.0, 0.0, 0.0, 0.0};
        double a_row = (asub == 0) ? (double)lrow : 0.0;
        double b_one = (asub == 0) ? 1.0 : 0.0;
        double a_one = (asub == 0) ? 1.0 : 0.0;
        double b_col = (asub == 0) ? (double)lrow : 0.0;
        prow = __builtin_amdgcn_mfma_f64_16x16x4f64(a_row, b_one, prow, 0, 0, 0);
        pcol = __builtin_amdgcn_mfma_f64_16x16x4f64(a_one, b_col, pcol, 0, 0, 0);
        #pragma unroll
        for (int r = 0; r < 4; ++r) { drow[r] = (int)prow[r]; dcol[r] = (int)pcol[r]; }
    }

    // ---- producer state: A-frags for 1 row-tile x 16 ksteps (loaded once) ----
    double afr[16];
    if (isprod) {
        const double* src = (w < 4) ? qp : kp;
        int arow = (w & 3) * 16 + lrow;
        #pragma unroll
        for (int ks = 0; ks < 16; ++ks)
            afr[ks] = src[(size_t)(b * 64 + arow) * INNER + h * 64 + ks * 4 + asub];
    }

    // ---- consumer state (waves 8-15): thread tile q in [qi*8, qi*8+8),
    //      k in [kb*4, kb*4+4), v-slice vs (16 v of each 64-chunk) ----
    int ci = t - 512;
    int qi = ci & 7;
    int kb = (ci >> 3) & 15;
    int vs = ci >> 7;                 // 0..3
    int qo[4];
    #pragma unroll
    for (int r = 0; r < 4; ++r) qo[r] = (4 * qi + ((r + qi) & 3)) * 2;
    int ko0 = 64 + 4 * kb;
    double best[8][4];
    #pragma unroll
    for (int a = 0; a < 8; ++a)
        #pragma unroll
        for (int b2 = 0; b2 < 4; ++b2) best[a][b2] = 0.0;

    __syncthreads();                  // sem init visible to all (only barrier)

    if (isprod) {
        for (int step = 0; step < 4; ++step) {
            if (step >= 2) {          // wait: consumers done with buf[step&1]
                for (;;) {
                    int c0 = 0;
                    if (l == 0) c0 = atomicAdd(&sem[4 + step - 2], 0);
                    if (__shfl(c0, 0) >= 8) break;
                    __builtin_amdgcn_s_sleep(2);
                }
            }
            int v0 = (cg * 4 + step) * CHUNKV;
            double* buf = S + (step & 1) * BUFD;
            vdbl4 acc[4];
            #pragma unroll
            for (int vt = 0; vt < 4; ++vt) acc[vt] = (vdbl4){0.0, 0.0, 0.0, 0.0};
            size_t base = (size_t)asub * VOCAB + v0 + lrow;
            double bcur[4], bnext[4];
            #pragma unroll
            for (int vt = 0; vt < 4; ++vt) bcur[vt] = dnt[base + vt * 16];
            #pragma unroll
            for (int ks = 0; ks < 16; ++ks) {
                if (ks < 15) {
                    size_t krow = base + (size_t)((ks + 1) * 4) * VOCAB;
                    #pragma unroll
                    for (int vt = 0; vt < 4; ++vt) bnext[vt] = dnt[krow + vt * 16];
                }
                #pragma unroll
                for (int vt = 0; vt < 4; ++vt)
                    acc[vt] = __builtin_amdgcn_mfma_f64_16x16x4f64(
                        afr[ks], bcur[vt], acc[vt], 0, 0, 0);
                if (ks < 15) {
                    #pragma unroll
                    for (int vt = 0; vt < 4; ++vt) bcur[vt] = bnext[vt];
                }
            }
            // pack: affine to [1.25,1.75], clear low 13 bits, embed (4095-v)<<1 on q
            // side; q stored at swizzled granule, k identity (see layout note).
            bool isq = (w < 4);
            #pragma unroll
            for (int vt = 0; vt < 4; ++vt)
                #pragma unroll
                for (int r = 0; r < 4; ++r) {
                    int vl = vt * 16 + dcol[r];
                    int grow = (w & 3) * 16 + drow[r];     // global row 0..63 within side
                    int slot;
                    if (isq) {
                        int qi8 = grow >> 3, rr = (grow >> 1) & 3;
                        slot = (4 * qi8 + ((rr + qi8) & 3)) * 2 + (grow & 1);
                    } else {
                        slot = 64 + grow;
                    }
                    unsigned long long code =
                        (unsigned long long)((4095 - (v0 + vl)) << 1);
                    double s = fma(acc[vt][r], 1.0 / 64.0, 1.5);
                    unsigned long long bb2 = __double_as_longlong(s) & ~0x1FFFull;
                    if (isq) bb2 |= code;
                    buf[vl * RS + slot] = __longlong_as_double(bb2);
                }
            __threadfence_block();    // LDS writes committed before signal
            if (l == 0) atomicAdd(&sem[step], 1);
        }
    } else {
        for (int step = 0; step < 4; ++step) {
            for (;;) {                // wait: all 8 producers packed chunk step
                int c0 = 0;
                if (l == 0) c0 = atomicAdd(&sem[step], 0);
                if (__shfl(c0, 0) >= 8) break;
                __builtin_amdgcn_s_sleep(2);
            }
            const double* row = S + (step & 1) * BUFD + vs * 16 * RS;
            #pragma unroll 2
            for (int vi = 0; vi < 16; ++vi, row += RS) {
                vdbl2 q0 = *(const vdbl2*)(row + qo[0]);
                vdbl2 q1 = *(const vdbl2*)(row + qo[1]);
                vdbl2 q2 = *(const vdbl2*)(row + qo[2]);
                vdbl2 q3 = *(const vdbl2*)(row + qo[3]);
                vdbl2 k0 = *(const vdbl2*)(row + ko0);
                vdbl2 k1 = *(const vdbl2*)(row + ko0 + 2);
                double qa[8] = {q0[0], q0[1], q1[0], q1[1],
                                q2[0], q2[1], q3[0], q3[1]};
                double kv0 = k0[0], kv1 = k0[1], kv2 = k1[0], kv3 = k1[1];
                #pragma unroll
                for (int a = 0; a < 8; ++a) {
                    best[a][0] = fmax(best[a][0], qa[a] + kv0);
                    best[a][1] = fmax(best[a][1], qa[a] + kv1);
                    best[a][2] = fmax(best[a][2], qa[a] + kv2);
                    best[a][3] = fmax(best[a][3], qa[a] + kv3);
                }
            }
            __threadfence_block();    // ds_reads complete before freeing buffer
            if (l == 0) atomicAdd(&sem[4 + step], 1);
        }
        // ---- cross-slice reduce: wait until ALL consumer waves left the
        //      buffers (red region aliases them), then tree-reduce in LDS ----
        for (;;) {
            int c0 = 0;
            if (l == 0) c0 = atomicAdd(&sem[7], 0);
            if (__shfl(c0, 0) >= 8) break;
            __builtin_amdgcn_s_sleep(2);
        }
        double* red = S;              // [32 pairs][512 threads] transposed
        #pragma unroll
        for (int a = 0; a < 8; ++a)
            #pragma unroll
            for (int b2 = 0; b2 < 4; ++b2)
                red[(a * 4 + b2) * 512 + ci] = best[a][b2];
        __threadfence_block();
        if (l == 0) atomicAdd(&sem[8], 1);
        if (ci < 128) {
            for (;;) {
                int c0 = 0;
                if (l == 0) c0 = atomicAdd(&sem[8], 0);
                if (__shfl(c0, 0) >= 8) break;
                __builtin_amdgcn_s_sleep(2);
            }
            #pragma unroll
            for (int j = 0; j < 32; ++j) {
                double m0 = fmax(red[j * 512 + ci], red[j * 512 + ci + 128]);
                double m1 = fmax(red[j * 512 + ci + 256], red[j * 512 + ci + 384]);
                double m = fmax(m0, m1);
                int q = qi * 8 + (j >> 2);
                int k = kb * 4 + (j & 3);
                // positive doubles: bit order == numeric order; max order-independent
                atomicMax(&bestf[((size_t)bh * 64 + q) * 64 + k],
                          (unsigned long long)__double_as_longlong(m));
            }
        }
    }
}

// ======== combine (r12 exact): 1024 blocks = q(64) x bh(16) ========
__global__ __launch_bounds__(256) void k_combine(
    const unsigned long long* __restrict__ bestf,
    const double* __restrict__ qp, const double* __restrict__ kp,
    const float* __restrict__ E,
    const float* __restrict__ lng, const float* __restrict__ lnb,
    float* __restrict__ out)
{
    int bid = blockIdx.x;             // 1024 = q(64) x bh(16)
    int bh = bid & 15, q = bid >> 4;
    int b = bh >> 3, h = bh & 7;
    int t = threadIdx.x;
    int w = t >> 6, lane = t & 63;

    __shared__ double qrow[64];
    __shared__ double gpart[4][64];
    __shared__ double knpart[4][64];
    __shared__ double qnpart[4];
    __shared__ float  ws_l[64];
    __shared__ int    idx_l[64];
    __shared__ float  epart[4][64];

    if (t < 64) qrow[t] = qp[(size_t)(b * 64 + q) * INNER + h * 64 + t];
    __syncthreads();

    {
        const double* krow = kp + (size_t)(b * 64 + lane) * INNER + h * 64 + w * 16;
        double gd = 0.0, kn = 0.0;
        #pragma unroll
        for (int i = 0; i < 16; ++i) {
            double xk = krow[i];
            gd = fma(qrow[w * 16 + i], xk, gd);
            kn = fma(xk, xk, kn);
        }
        gpart[w][lane] = gd;
        knpart[w][lane] = kn;
        if (lane == 0) {
            double qn = 0.0;
            #pragma unroll
            for (int i = 0; i < 16; ++i) { double xq = qrow[w * 16 + i]; qn = fma(xq, xq, qn); }
            qnpart[w] = qn;
        }
    }
    __syncthreads();

    if (w == 0) {
        int k = lane;
        double gdot = (gpart[0][k] + gpart[1][k]) + (gpart[2][k] + gpart[3][k]);
        double kn2  = (knpart[0][k] + knpart[1][k]) + (knpart[2][k] + knpart[3][k]);
        double qn2  = (qnpart[0] + qnpart[1]) + (qnpart[2] + qnpart[3]);
        unsigned long long bb = bestf[((size_t)bh * 64 + q) * 64 + k];
        int vidx = 4095 - (int)(bb & 0xFFFull);
        double sval = __longlong_as_double(bb & ~0x1FFFull);
        double tru = (sval - 3.0) * 64.0;
        double n2 = qn2 + kn2 + 2.0 * gdot;
        double wsim = tru * (1.0 / sqrt(fmax(n2, 1e-12)));
        size_t oidx = ((size_t)(b * QLEN + q) * KLEN + k) * NH + h;
        out[65536 + oidx] = (float)vidx;          // out_ids as float32
        out[131072 + oidx] = (float)wsim;         // r3_scores
        ws_l[k] = (float)wsim;
        idx_l[k] = vidx;
    }
    __syncthreads();

    {
        int d = lane;
        float acc = 0.0f;
        #pragma unroll 4
        for (int k2 = w * 16; k2 < w * 16 + 16; ++k2)
            acc += E[idx_l[k2] * DKV + d] * ws_l[k2];
        epart[w][d] = acc;
    }
    __syncthreads();

    if (w == 0) {
        int d = lane;
        float acc = ((epart[0][d] + epart[1][d]) + (epart[2][d] + epart[3][d])) * (1.0f / 64.0f);
        float mean = acc;
        for (int m = 32; m >= 1; m >>= 1) mean += __shfl_xor(mean, m);
        mean *= (1.0f / 64.0f);
        float dv = acc - mean;
        float var = dv * dv;
        for (int m = 32; m >= 1; m >>= 1) var += __shfl_xor(var, m);
        var *= (1.0f / 64.0f);
        float o = dv * rsqrtf(var + 1e-6f) * lng[d] + lnb[d];
        out[(((size_t)b * NH + h) * QLEN + q) * DKV + d] = o;
    }
}

extern "C" void kernel_launch(void* const* d_in, const int* in_sizes, int n_in,
                              void* d_out, int out_size, void* d_ws, size_t ws_size,
                              hipStream_t stream) {
    const float* query = (const float*)d_in[0];
    const float* key   = (const float*)d_in[1];
    const float* qpe   = (const float*)d_in[2];
    const float* kpe   = (const float*)d_in[3];
    const float* wi    = (const float*)d_in[4];
    const float* vq    = (const float*)d_in[5];
    const float* vqg   = (const float*)d_in[6];
    const float* vqb   = (const float*)d_in[7];
    const float* ow    = (const float*)d_in[8];
    const float* lng   = (const float*)d_in[9];
    const float* lnb   = (const float*)d_in[10];
    float* out = (float*)d_out;

    char* ws = (char*)d_ws;
    double* qp  = (double*)(ws + 0);
    double* kp  = (double*)(ws + 524288);
    double* dnt = (double*)(ws + 1048576);
    float*  E   = (float*) (ws + 3145728);
    unsigned long long* bestf = (unsigned long long*)(ws + 4194304);

    k_prep   <<<2048, 256, 0, stream>>>(query, key, qpe, kpe, wi, vq, vqg, vqb, ow,
                                        qp, kp, dnt, E, bestf);
    k_simscan<<<256, 1024, 0, stream>>>(qp, kp, dnt, bestf);
    k_combine<<<1024, 256, 0, stream>>>(bestf, qp, kp, E, lng, lnb, out);
}

// Round 3
// 168.470 us; speedup vs baseline: 1.0011x; 1.0011x over previous
//
#include <hip/hip_runtime.h>
#include <math.h>

#define BS 2
#define QLEN 64
#define KLEN 64
#define NH 8
#define DKV 64
#define INNER 512
#define VOCAB 4096
#define CHUNKV 64
#define RS 130               // Cv stride (doubles), even -> 16B-aligned b128 reads
#define BUFD (CHUNKV * RS)   // 8320 doubles per buffer

typedef double vdbl4 __attribute__((ext_vector_type(4)));
typedef double vdbl2 __attribute__((ext_vector_type(2)));

// ---------------- workspace layout (bytes) ----------------
// qp    : [BS][64][INNER] double  @ 0        (512 KB)
// kp    : [BS][64][INNER] double  @ 512 KB   (512 KB)
// dnt   : [DKV][VOCAB]    double  @ 1 MB     (2 MB)   l2-normalized dict, transposed
// E     : [VOCAB][DKV]    float   @ 3 MB     (1 MB)   LN(dict) @ vq_o_w
// bestf : [16][64][64]    u64     @ 4 MB     (512 KB) atomicMax'd packed (val | 4095-v code)

// ======== prep: proj GEMM (blocks 0..1023) + dict (blocks 1024..2047) — r12 exact ========
__global__ __launch_bounds__(256) void k_prep(
    const float* __restrict__ q_in, const float* __restrict__ k_in,
    const float* __restrict__ qpe, const float* __restrict__ kpe,
    const float* __restrict__ wi,
    const float* __restrict__ vq, const float* __restrict__ g,
    const float* __restrict__ bta, const float* __restrict__ ow,
    double* __restrict__ qp, double* __restrict__ kp,
    double* __restrict__ dnt, float* __restrict__ E,
    unsigned long long* __restrict__ bestf)
{
    __shared__ double S[1600];           // proj: xs[1024]+red[512]; dict: Lsh[256]+Dsh[320]
    __shared__ float Osh[4096];          // dict: ow cache
    int bid = blockIdx.x;
    int t = threadIdx.x;

    if (bid < 1024) {
        int side = bid >> 9;
        int b    = (bid >> 8) & 1;
        int rp   = (bid >> 3) & 31;
        int cb   = bid & 7;
        const float* xin = side ? k_in : q_in;
        const float* pin = side ? kpe : qpe;
        double* outp = side ? kp : qp;
        int wrow0 = side ? INNER : 0;
        int r0 = rp * 2;
        double* xs = S;                  // [2][512]
        double* red = S + 1024;          // [dh*2+rr][64]
        for (int i = t; i < 2 * INNER; i += 256) {
            int rr = i >> 9, dd = i & 511;
            int gidx = (b * 64 + r0 + rr) * INNER + dd;
            xs[rr * INNER + dd] = (double)xin[gidx] + (double)pin[gidx];
        }
        __syncthreads();
        int col = cb * 64 + (t & 63);
        int dh = t >> 6;
        double a0 = 0.0, a1 = 0.0;
        #pragma unroll 8
        for (int d = dh * 128; d < dh * 128 + 128; ++d) {
            double w = (double)wi[(size_t)(wrow0 + d) * INNER + col];
            a0 = fma(xs[d], w, a0);
            a1 = fma(xs[INNER + d], w, a1);
        }
        red[(dh * 2 + 0) * 64 + (t & 63)] = a0;
        red[(dh * 2 + 1) * 64 + (t & 63)] = a1;
        __syncthreads();
        if (t < 128) {
            int rr = t >> 6, c2 = t & 63;
            double s = (red[(0 * 2 + rr) * 64 + c2] + red[(1 * 2 + rr) * 64 + c2])
                     + (red[(2 * 2 + rr) * 64 + c2] + red[(3 * 2 + rr) * 64 + c2]);
            outp[(size_t)(b * 64 + r0 + rr) * INNER + cb * 64 + c2] = s;
        }
    } else {
        int db = bid - 1024;             // 0..1023, 4 vocab rows each (1 per wave)
        if (db < 256) bestf[db * 256 + t] = 0ull;
        double* Lsh = S;                 // [wave(4)][64] LN values
        double* Dsh = S + 256;           // [j(64)][5] dn staging (vloc = wave)
        int vb = db * 4;
        int wv = t >> 6, lane = t & 63;
        for (int i = t; i < 4096; i += 256) Osh[i] = ow[i];
        int v = vb + wv;
        double z = (double)vq[v * DKV + lane];
        double s2 = z * z, s1 = z;
        for (int m = 32; m >= 1; m >>= 1) { s2 += __shfl_xor(s2, m); s1 += __shfl_xor(s1, m); }
        Dsh[lane * 5 + wv] = z * (1.0 / sqrt(fmax(s2, 1e-12)));
        double mean = s1 * (1.0 / 64.0);
        double d0 = z - mean;
        double vv2 = d0 * d0;
        for (int m = 32; m >= 1; m >>= 1) vv2 += __shfl_xor(vv2, m);
        vv2 *= (1.0 / 64.0);
        Lsh[wv * 64 + lane] = d0 * (1.0 / sqrt(vv2 + 1e-6)) * (double)g[lane] + (double)bta[lane];
        __syncthreads();
        double c0 = 0.0, c1 = 0.0, c2 = 0.0, c3 = 0.0;
        #pragma unroll 4
        for (int gg = 0; gg < 16; ++gg) {
            int jj = gg * 4;
            c0 = fma(Lsh[wv * 64 + jj + 0], (double)Osh[(jj + 0) * 64 + lane], c0);
            c1 = fma(Lsh[wv * 64 + jj + 1], (double)Osh[(jj + 1) * 64 + lane], c1);
            c2 = fma(Lsh[wv * 64 + jj + 2], (double)Osh[(jj + 2) * 64 + lane], c2);
            c3 = fma(Lsh[wv * 64 + jj + 3], (double)Osh[(jj + 3) * 64 + lane], c3);
        }
        E[v * DKV + lane] = (float)((c0 + c1) + (c2 + c3));
        {
            int j = t >> 2, vloc = t & 3;
            dnt[(size_t)j * VOCAB + vb + vloc] = Dsh[j * 5 + vloc];
        }
    }
}

// ======== producer/consumer MFMA-f64 sim + scan — LDS-semaphore sync ========
// r12 pipeline; consumer 8x4 register blocking (r1) + VGPR-cap fix (r2):
//   __launch_bounds__(1024, 1) -> allocator may use up to the structural
//   128-VGPR cap (16 waves/block = 4 waves/SIMD). The (1024,4) bound capped
//   at 64 VGPRs and spilled best[8][4] to scratch (r1: WRITE_SIZE 8->32 MB,
//   dur 61->78us). LDS still limits to 1 block/CU, so occupancy unchanged.
// LDS layout per v-row (RS=130 dbl): [0..63]=q (granule-swizzled:
//   p = 4*qi + ((r+qi)&3), 2-way-free reads), [64..127]=k (identity; natural
//   32B stride is already 2-way-free), [128..129] pad.
__global__ __launch_bounds__(1024, 1) void k_simscan(
    const double* __restrict__ qp, const double* __restrict__ kp,
    const double* __restrict__ dnt,
    unsigned long long* __restrict__ bestf)
{
    int bid = blockIdx.x;             // 256 = cg(16) x bh(16)
    int bh = bid & 15, cg = bid >> 4;
    int b = bh >> 3, h = bh & 7;
    int t = threadIdx.x;
    int w = t >> 6, l = t & 63;

    __shared__ double S[2 * BUFD];    // 133120 B -> 1 block/CU
    __shared__ int sem[9];            // [0..3]=prod_cnt, [4..7]=cons_cnt, [8]=red_cnt

    int asub = l >> 4;
    int lrow = l & 15;
    bool isprod = (w < 8);

    if (t < 9) sem[t] = 0;

    // ---- D-layout probes (verified calibration, rounds 6-15) ----
    int drow[4], dcol[4];
    {
        vdbl4 prow = (vdbl4){0.0, 0.0, 0.0, 0.0};
        vdbl4 pcol = (vdbl4){0.0, 0.0, 0.0, 0.0};
        double a_row = (asub == 0) ? (double)lrow : 0.0;
        double b_one = (asub == 0) ? 1.0 : 0.0;
        double a_one = (asub == 0) ? 1.0 : 0.0;
        double b_col = (asub == 0) ? (double)lrow : 0.0;
        prow = __builtin_amdgcn_mfma_f64_16x16x4f64(a_row, b_one, prow, 0, 0, 0);
        pcol = __builtin_amdgcn_mfma_f64_16x16x4f64(a_one, b_col, pcol, 0, 0, 0);
        #pragma unroll
        for (int r = 0; r < 4; ++r) { drow[r] = (int)prow[r]; dcol[r] = (int)pcol[r]; }
    }

    // ---- producer state: A-frags for 1 row-tile x 16 ksteps (loaded once) ----
    double afr[16];
    if (isprod) {
        const double* src = (w < 4) ? qp : kp;
        int arow = (w & 3) * 16 + lrow;
        #pragma unroll
        for (int ks = 0; ks < 16; ++ks)
            afr[ks] = src[(size_t)(b * 64 + arow) * INNER + h * 64 + ks * 4 + asub];
    }

    // ---- consumer state (waves 8-15): thread tile q in [qi*8, qi*8+8),
    //      k in [kb*4, kb*4+4), v-slice vs (16 v of each 64-chunk) ----
    int ci = t - 512;
    int qi = ci & 7;
    int kb = (ci >> 3) & 15;
    int vs = ci >> 7;                 // 0..3
    int qo[4];
    #pragma unroll
    for (int r = 0; r < 4; ++r) qo[r] = (4 * qi + ((r + qi) & 3)) * 2;
    int ko0 = 64 + 4 * kb;
    double best[8][4];
    #pragma unroll
    for (int a = 0; a < 8; ++a)
        #pragma unroll
        for (int b2 = 0; b2 < 4; ++b2) best[a][b2] = 0.0;

    __syncthreads();                  // sem init visible to all (only barrier)

    if (isprod) {
        for (int step = 0; step < 4; ++step) {
            if (step >= 2) {          // wait: consumers done with buf[step&1]
                for (;;) {
                    int c0 = 0;
                    if (l == 0) c0 = atomicAdd(&sem[4 + step - 2], 0);
                    if (__shfl(c0, 0) >= 8) break;
                    __builtin_amdgcn_s_sleep(2);
                }
            }
            int v0 = (cg * 4 + step) * CHUNKV;
            double* buf = S + (step & 1) * BUFD;
            vdbl4 acc[4];
            #pragma unroll
            for (int vt = 0; vt < 4; ++vt) acc[vt] = (vdbl4){0.0, 0.0, 0.0, 0.0};
            size_t base = (size_t)asub * VOCAB + v0 + lrow;
            double bcur[4], bnext[4];
            #pragma unroll
            for (int vt = 0; vt < 4; ++vt) bcur[vt] = dnt[base + vt * 16];
            #pragma unroll
            for (int ks = 0; ks < 16; ++ks) {
                if (ks < 15) {
                    size_t krow = base + (size_t)((ks + 1) * 4) * VOCAB;
                    #pragma unroll
                    for (int vt = 0; vt < 4; ++vt) bnext[vt] = dnt[krow + vt * 16];
                }
                #pragma unroll
                for (int vt = 0; vt < 4; ++vt)
                    acc[vt] = __builtin_amdgcn_mfma_f64_16x16x4f64(
                        afr[ks], bcur[vt], acc[vt], 0, 0, 0);
                if (ks < 15) {
                    #pragma unroll
                    for (int vt = 0; vt < 4; ++vt) bcur[vt] = bnext[vt];
                }
            }
            // pack: affine to [1.25,1.75], clear low 13 bits, embed (4095-v)<<1 on q
            // side; q stored at swizzled granule, k identity (see layout note).
            bool isq = (w < 4);
            #pragma unroll
            for (int vt = 0; vt < 4; ++vt)
                #pragma unroll
                for (int r = 0; r < 4; ++r) {
                    int vl = vt * 16 + dcol[r];
                    int grow = (w & 3) * 16 + drow[r];     // global row 0..63 within side
                    int slot;
                    if (isq) {
                        int qi8 = grow >> 3, rr = (grow >> 1) & 3;
                        slot = (4 * qi8 + ((rr + qi8) & 3)) * 2 + (grow & 1);
                    } else {
                        slot = 64 + grow;
                    }
                    unsigned long long code =
                        (unsigned long long)((4095 - (v0 + vl)) << 1);
                    double s = fma(acc[vt][r], 1.0 / 64.0, 1.5);
                    unsigned long long bb2 = __double_as_longlong(s) & ~0x1FFFull;
                    if (isq) bb2 |= code;
                    buf[vl * RS + slot] = __longlong_as_double(bb2);
                }
            __threadfence_block();    // LDS writes committed before signal
            if (l == 0) atomicAdd(&sem[step], 1);
        }
    } else {
        for (int step = 0; step < 4; ++step) {
            for (;;) {                // wait: all 8 producers packed chunk step
                int c0 = 0;
                if (l == 0) c0 = atomicAdd(&sem[step], 0);
                if (__shfl(c0, 0) >= 8) break;
                __builtin_amdgcn_s_sleep(2);
            }
            const double* row = S + (step & 1) * BUFD + vs * 16 * RS;
            #pragma unroll 2
            for (int vi = 0; vi < 16; ++vi, row += RS) {
                vdbl2 q0 = *(const vdbl2*)(row + qo[0]);
                vdbl2 q1 = *(const vdbl2*)(row + qo[1]);
                vdbl2 q2 = *(const vdbl2*)(row + qo[2]);
                vdbl2 q3 = *(const vdbl2*)(row + qo[3]);
                vdbl2 k0 = *(const vdbl2*)(row + ko0);
                vdbl2 k1 = *(const vdbl2*)(row + ko0 + 2);
                double qa[8] = {q0[0], q0[1], q1[0], q1[1],
                                q2[0], q2[1], q3[0], q3[1]};
                double kv0 = k0[0], kv1 = k0[1], kv2 = k1[0], kv3 = k1[1];
                #pragma unroll
                for (int a = 0; a < 8; ++a) {
                    best[a][0] = fmax(best[a][0], qa[a] + kv0);
                    best[a][1] = fmax(best[a][1], qa[a] + kv1);
                    best[a][2] = fmax(best[a][2], qa[a] + kv2);
                    best[a][3] = fmax(best[a][3], qa[a] + kv3);
                }
            }
            __threadfence_block();    // ds_reads complete before freeing buffer
            if (l == 0) atomicAdd(&sem[4 + step], 1);
        }
        // ---- cross-slice reduce: wait until ALL consumer waves left the
        //      buffers (red region aliases them), then tree-reduce in LDS ----
        for (;;) {
            int c0 = 0;
            if (l == 0) c0 = atomicAdd(&sem[7], 0);
            if (__shfl(c0, 0) >= 8) break;
            __builtin_amdgcn_s_sleep(2);
        }
        double* red = S;              // [32 pairs][512 threads] transposed
        #pragma unroll
        for (int a = 0; a < 8; ++a)
            #pragma unroll
            for (int b2 = 0; b2 < 4; ++b2)
                red[(a * 4 + b2) * 512 + ci] = best[a][b2];
        __threadfence_block();
        if (l == 0) atomicAdd(&sem[8], 1);
        if (ci < 128) {
            for (;;) {
                int c0 = 0;
                if (l == 0) c0 = atomicAdd(&sem[8], 0);
                if (__shfl(c0, 0) >= 8) break;
                __builtin_amdgcn_s_sleep(2);
            }
            #pragma unroll
            for (int j = 0; j < 32; ++j) {
                double m0 = fmax(red[j * 512 + ci], red[j * 512 + ci + 128]);
                double m1 = fmax(red[j * 512 + ci + 256], red[j * 512 + ci + 384]);
                double m = fmax(m0, m1);
                int q = qi * 8 + (j >> 2);
                int k = kb * 4 + (j & 3);
                // positive doubles: bit order == numeric order; max order-independent
                atomicMax(&bestf[((size_t)bh * 64 + q) * 64 + k],
                          (unsigned long long)__double_as_longlong(m));
            }
        }
    }
}

// ======== combine (r12 exact): 1024 blocks = q(64) x bh(16) ========
__global__ __launch_bounds__(256) void k_combine(
    const unsigned long long* __restrict__ bestf,
    const double* __restrict__ qp, const double* __restrict__ kp,
    const float* __restrict__ E,
    const float* __restrict__ lng, const float* __restrict__ lnb,
    float* __restrict__ out)
{
    int bid = blockIdx.x;             // 1024 = q(64) x bh(16)
    int bh = bid & 15, q = bid >> 4;
    int b = bh >> 3, h = bh & 7;
    int t = threadIdx.x;
    int w = t >> 6, lane = t & 63;

    __shared__ double qrow[64];
    __shared__ double gpart[4][64];
    __shared__ double knpart[4][64];
    __shared__ double qnpart[4];
    __shared__ float  ws_l[64];
    __shared__ int    idx_l[64];
    __shared__ float  epart[4][64];

    if (t < 64) qrow[t] = qp[(size_t)(b * 64 + q) * INNER + h * 64 + t];
    __syncthreads();

    {
        const double* krow = kp + (size_t)(b * 64 + lane) * INNER + h * 64 + w * 16;
        double gd = 0.0, kn = 0.0;
        #pragma unroll
        for (int i = 0; i < 16; ++i) {
            double xk = krow[i];
            gd = fma(qrow[w * 16 + i], xk, gd);
            kn = fma(xk, xk, kn);
        }
        gpart[w][lane] = gd;
        knpart[w][lane] = kn;
        if (lane == 0) {
            double qn = 0.0;
            #pragma unroll
            for (int i = 0; i < 16; ++i) { double xq = qrow[w * 16 + i]; qn = fma(xq, xq, qn); }
            qnpart[w] = qn;
        }
    }
    __syncthreads();

    if (w == 0) {
        int k = lane;
        double gdot = (gpart[0][k] + gpart[1][k]) + (gpart[2][k] + gpart[3][k]);
        double kn2  = (knpart[0][k] + knpart[1][k]) + (knpart[2][k] + knpart[3][k]);
        double qn2  = (qnpart[0] + qnpart[1]) + (qnpart[2] + qnpart[3]);
        unsigned long long bb = bestf[((size_t)bh * 64 + q) * 64 + k];
        int vidx = 4095 - (int)(bb & 0xFFFull);
        double sval = __longlong_as_double(bb & ~0x1FFFull);
        double tru = (sval - 3.0) * 64.0;
        double n2 = qn2 + kn2 + 2.0 * gdot;
        double wsim = tru * (1.0 / sqrt(fmax(n2, 1e-12)));
        size_t oidx = ((size_t)(b * QLEN + q) * KLEN + k) * NH + h;
        out[65536 + oidx] = (float)vidx;          // out_ids as float32
        out[131072 + oidx] = (float)wsim;         // r3_scores
        ws_l[k] = (float)wsim;
        idx_l[k] = vidx;
    }
    __syncthreads();

    {
        int d = lane;
        float acc = 0.0f;
        #pragma unroll 4
        for (int k2 = w * 16; k2 < w * 16 + 16; ++k2)
            acc += E[idx_l[k2] * DKV + d] * ws_l[k2];
        epart[w][d] = acc;
    }
    __syncthreads();

    if (w == 0) {
        int d = lane;
        float acc = ((epart[0][d] + epart[1][d]) + (epart[2][d] + epart[3][d])) * (1.0f / 64.0f);
        float mean = acc;
        for (int m = 32; m >= 1; m >>= 1) mean += __shfl_xor(mean, m);
        mean *= (1.0f / 64.0f);
        float dv = acc - mean;
        float var = dv * dv;
        for (int m = 32; m >= 1; m >>= 1) var += __shfl_xor(var, m);
        var *= (1.0f / 64.0f);
        float o = dv * rsqrtf(var + 1e-6f) * lng[d] + lnb[d];
        out[(((size_t)b * NH + h) * QLEN + q) * DKV + d] = o;
    }
}

extern "C" void kernel_launch(void* const* d_in, const int* in_sizes, int n_in,
                              void* d_out, int out_size, void* d_ws, size_t ws_size,
                              hipStream_t stream) {
    const float* query = (const float*)d_in[0];
    const float* key   = (const float*)d_in[1];
    const float* qpe   = (const float*)d_in[2];
    const float* kpe   = (const float*)d_in[3];
    const float* wi    = (const float*)d_in[4];
    const float* vq    = (const float*)d_in[5];
    const float* vqg   = (const float*)d_in[6];
    const float* vqb   = (const float*)d_in[7];
    const float* ow    = (const float*)d_in[8];
    const float* lng   = (const float*)d_in[9];
    const float* lnb   = (const float*)d_in[10];
    float* out = (float*)d_out;

    char* ws = (char*)d_ws;
    double* qp  = (double*)(ws + 0);
    double* kp  = (double*)(ws + 524288);
    double* dnt = (double*)(ws + 1048576);
    float*  E   = (float*) (ws + 3145728);
    unsigned long long* bestf = (unsigned long long*)(ws + 4194304);

    k_prep   <<<2048, 256, 0, stream>>>(query, key, qpe, kpe, wi, vq, vqg, vqb, ow,
                                        qp, kp, dnt, E, bestf);
    k_simscan<<<256, 1024, 0, stream>>>(qp, kp, dnt, bestf);
    k_combine<<<1024, 256, 0, stream>>>(bestf, qp, kp, E, lng, lnb, out);
}

// Round 4
// 167.520 us; speedup vs baseline: 1.0067x; 1.0057x over previous
//
#include <hip/hip_runtime.h>
#include <math.h>

#define BS 2
#define QLEN 64
#define KLEN 64
#define NH 8
#define DKV 64
#define INNER 512
#define VOCAB 4096
#define CHUNKV 64
#define RS 130               // Cv stride (doubles), even -> 16B-aligned b128 reads
#define BUFD (CHUNKV * RS)   // 8320 doubles per buffer

typedef double vdbl4 __attribute__((ext_vector_type(4)));
typedef double vdbl2 __attribute__((ext_vector_type(2)));

// ---------------- workspace layout (bytes) ----------------
// qp    : [BS][64][INNER] double  @ 0        (512 KB)
// kp    : [BS][64][INNER] double  @ 512 KB   (512 KB)
// dnt   : [DKV][VOCAB]    double  @ 1 MB     (2 MB)   l2-normalized dict, transposed
// E     : [VOCAB][DKV]    float   @ 3 MB     (1 MB)   LN(dict) @ vq_o_w
// bestf : [16][64][64]    u64     @ 4 MB     (512 KB) atomicMax'd packed (val | 4095-v code)

// ======== prep: proj GEMM (blocks 0..1023) + dict (blocks 1024..2047) — r12 exact ========
__global__ __launch_bounds__(256) void k_prep(
    const float* __restrict__ q_in, const float* __restrict__ k_in,
    const float* __restrict__ qpe, const float* __restrict__ kpe,
    const float* __restrict__ wi,
    const float* __restrict__ vq, const float* __restrict__ g,
    const float* __restrict__ bta, const float* __restrict__ ow,
    double* __restrict__ qp, double* __restrict__ kp,
    double* __restrict__ dnt, float* __restrict__ E,
    unsigned long long* __restrict__ bestf)
{
    __shared__ double S[1600];           // proj: xs[1024]+red[512]; dict: Lsh[256]+Dsh[320]
    __shared__ float Osh[4096];          // dict: ow cache
    int bid = blockIdx.x;
    int t = threadIdx.x;

    if (bid < 1024) {
        int side = bid >> 9;
        int b    = (bid >> 8) & 1;
        int rp   = (bid >> 3) & 31;
        int cb   = bid & 7;
        const float* xin = side ? k_in : q_in;
        const float* pin = side ? kpe : qpe;
        double* outp = side ? kp : qp;
        int wrow0 = side ? INNER : 0;
        int r0 = rp * 2;
        double* xs = S;                  // [2][512]
        double* red = S + 1024;          // [dh*2+rr][64]
        for (int i = t; i < 2 * INNER; i += 256) {
            int rr = i >> 9, dd = i & 511;
            int gidx = (b * 64 + r0 + rr) * INNER + dd;
            xs[rr * INNER + dd] = (double)xin[gidx] + (double)pin[gidx];
        }
        __syncthreads();
        int col = cb * 64 + (t & 63);
        int dh = t >> 6;
        double a0 = 0.0, a1 = 0.0;
        #pragma unroll 8
        for (int d = dh * 128; d < dh * 128 + 128; ++d) {
            double w = (double)wi[(size_t)(wrow0 + d) * INNER + col];
            a0 = fma(xs[d], w, a0);
            a1 = fma(xs[INNER + d], w, a1);
        }
        red[(dh * 2 + 0) * 64 + (t & 63)] = a0;
        red[(dh * 2 + 1) * 64 + (t & 63)] = a1;
        __syncthreads();
        if (t < 128) {
            int rr = t >> 6, c2 = t & 63;
            double s = (red[(0 * 2 + rr) * 64 + c2] + red[(1 * 2 + rr) * 64 + c2])
                     + (red[(2 * 2 + rr) * 64 + c2] + red[(3 * 2 + rr) * 64 + c2]);
            outp[(size_t)(b * 64 + r0 + rr) * INNER + cb * 64 + c2] = s;
        }
    } else {
        int db = bid - 1024;             // 0..1023, 4 vocab rows each (1 per wave)
        if (db < 256) bestf[db * 256 + t] = 0ull;
        double* Lsh = S;                 // [wave(4)][64] LN values
        double* Dsh = S + 256;           // [j(64)][5] dn staging (vloc = wave)
        int vb = db * 4;
        int wv = t >> 6, lane = t & 63;
        for (int i = t; i < 4096; i += 256) Osh[i] = ow[i];
        int v = vb + wv;
        double z = (double)vq[v * DKV + lane];
        double s2 = z * z, s1 = z;
        for (int m = 32; m >= 1; m >>= 1) { s2 += __shfl_xor(s2, m); s1 += __shfl_xor(s1, m); }
        Dsh[lane * 5 + wv] = z * (1.0 / sqrt(fmax(s2, 1e-12)));
        double mean = s1 * (1.0 / 64.0);
        double d0 = z - mean;
        double vv2 = d0 * d0;
        for (int m = 32; m >= 1; m >>= 1) vv2 += __shfl_xor(vv2, m);
        vv2 *= (1.0 / 64.0);
        Lsh[wv * 64 + lane] = d0 * (1.0 / sqrt(vv2 + 1e-6)) * (double)g[lane] + (double)bta[lane];
        __syncthreads();
        double c0 = 0.0, c1 = 0.0, c2 = 0.0, c3 = 0.0;
        #pragma unroll 4
        for (int gg = 0; gg < 16; ++gg) {
            int jj = gg * 4;
            c0 = fma(Lsh[wv * 64 + jj + 0], (double)Osh[(jj + 0) * 64 + lane], c0);
            c1 = fma(Lsh[wv * 64 + jj + 1], (double)Osh[(jj + 1) * 64 + lane], c1);
            c2 = fma(Lsh[wv * 64 + jj + 2], (double)Osh[(jj + 2) * 64 + lane], c2);
            c3 = fma(Lsh[wv * 64 + jj + 3], (double)Osh[(jj + 3) * 64 + lane], c3);
        }
        E[v * DKV + lane] = (float)((c0 + c1) + (c2 + c3));
        {
            int j = t >> 2, vloc = t & 3;
            dnt[(size_t)j * VOCAB + vb + vloc] = Dsh[j * 5 + vloc];
        }
    }
}

// ======== producer/consumer MFMA-f64 sim + scan — LDS-semaphore sync ========
// r12 pipeline. r4: consumer retiled to 4x4 (best[4][4]=32 VGPR) with P=2
// v-slices, sized to FIT the empirical 64-arch-VGPR cap (r1/r3: 8x4 spilled
// 24MB to scratch at VGPR_Count=64 regardless of launch_bounds; producer fits
// because MFMA acc lives in AGPRs). Per v: 2x ds_read_b128 (4 consecutive q,
// 4 consecutive k) -> 16 updates, identity slot layout (no permutation).
// LDS per v-row (RS=130 dbl): [0..63]=q, [64..127]=k, [128..129] pad.
__global__ __launch_bounds__(1024, 4) void k_simscan(
    const double* __restrict__ qp, const double* __restrict__ kp,
    const double* __restrict__ dnt,
    unsigned long long* __restrict__ bestf)
{
    int bid = blockIdx.x;             // 256 = cg(16) x bh(16)
    int bh = bid & 15, cg = bid >> 4;
    int b = bh >> 3, h = bh & 7;
    int t = threadIdx.x;
    int w = t >> 6, l = t & 63;

    __shared__ double S[2 * BUFD];    // 133120 B -> 1 block/CU
    __shared__ int sem[9];            // [0..3]=prod_cnt, [4..7]=cons_cnt, [8]=red_cnt

    int asub = l >> 4;
    int lrow = l & 15;
    bool isprod = (w < 8);

    if (t < 9) sem[t] = 0;

    // ---- D-layout probes (verified calibration, rounds 6-15) ----
    int drow[4], dcol[4];
    {
        vdbl4 prow = (vdbl4){0.0, 0.0, 0.0, 0.0};
        vdbl4 pcol = (vdbl4){0.0, 0.0, 0.0, 0.0};
        double a_row = (asub == 0) ? (double)lrow : 0.0;
        double b_one = (asub == 0) ? 1.0 : 0.0;
        double a_one = (asub == 0) ? 1.0 : 0.0;
        double b_col = (asub == 0) ? (double)lrow : 0.0;
        prow = __builtin_amdgcn_mfma_f64_16x16x4f64(a_row, b_one, prow, 0, 0, 0);
        pcol = __builtin_amdgcn_mfma_f64_16x16x4f64(a_one, b_col, pcol, 0, 0, 0);
        #pragma unroll
        for (int r = 0; r < 4; ++r) { drow[r] = (int)prow[r]; dcol[r] = (int)pcol[r]; }
    }

    // ---- producer state: A-frags for 1 row-tile x 16 ksteps (loaded once) ----
    double afr[16];
    if (isprod) {
        const double* src = (w < 4) ? qp : kp;
        int arow = (w & 3) * 16 + lrow;
        #pragma unroll
        for (int ks = 0; ks < 16; ++ks)
            afr[ks] = src[(size_t)(b * 64 + arow) * INNER + h * 64 + ks * 4 + asub];
    }

    // ---- consumer state (waves 8-15): thread tile q in [qi*4, qi*4+4),
    //      k in [kb*4, kb*4+4), v-slice vs in {0,1} (32 v of each 64-chunk) ----
    int ci = t - 512;
    int qi = ci & 15;
    int kb = (ci >> 4) & 15;
    int vs = ci >> 8;                 // 0..1 (wave-uniform)
    double best[4][4];
    #pragma unroll
    for (int a = 0; a < 4; ++a)
        #pragma unroll
        for (int b2 = 0; b2 < 4; ++b2) best[a][b2] = 0.0;

    __syncthreads();                  // sem init visible to all (only barrier)

    if (isprod) {
        for (int step = 0; step < 4; ++step) {
            if (step >= 2) {          // wait: consumers done with buf[step&1]
                for (;;) {
                    int c0 = 0;
                    if (l == 0) c0 = atomicAdd(&sem[4 + step - 2], 0);
                    if (__shfl(c0, 0) >= 8) break;
                    __builtin_amdgcn_s_sleep(2);
                }
            }
            int v0 = (cg * 4 + step) * CHUNKV;
            double* buf = S + (step & 1) * BUFD;
            vdbl4 acc[4];
            #pragma unroll
            for (int vt = 0; vt < 4; ++vt) acc[vt] = (vdbl4){0.0, 0.0, 0.0, 0.0};
            size_t base = (size_t)asub * VOCAB + v0 + lrow;
            double bcur[4], bnext[4];
            #pragma unroll
            for (int vt = 0; vt < 4; ++vt) bcur[vt] = dnt[base + vt * 16];
            #pragma unroll
            for (int ks = 0; ks < 16; ++ks) {
                if (ks < 15) {
                    size_t krow = base + (size_t)((ks + 1) * 4) * VOCAB;
                    #pragma unroll
                    for (int vt = 0; vt < 4; ++vt) bnext[vt] = dnt[krow + vt * 16];
                }
                #pragma unroll
                for (int vt = 0; vt < 4; ++vt)
                    acc[vt] = __builtin_amdgcn_mfma_f64_16x16x4f64(
                        afr[ks], bcur[vt], acc[vt], 0, 0, 0);
                if (ks < 15) {
                    #pragma unroll
                    for (int vt = 0; vt < 4; ++vt) bcur[vt] = bnext[vt];
                }
            }
            // pack: affine to [1.25,1.75], clear low 13 bits, embed (4095-v)<<1 on q
            // side; identity slots: q index -> slot, k index -> 64+slot.
            bool isq = (w < 4);
            #pragma unroll
            for (int vt = 0; vt < 4; ++vt)
                #pragma unroll
                for (int r = 0; r < 4; ++r) {
                    int vl = vt * 16 + dcol[r];
                    int grow = (w & 3) * 16 + drow[r];     // global row 0..63 within side
                    int slot = isq ? grow : (64 + grow);
                    unsigned long long code =
                        (unsigned long long)((4095 - (v0 + vl)) << 1);
                    double s = fma(acc[vt][r], 1.0 / 64.0, 1.5);
                    unsigned long long bb2 = __double_as_longlong(s) & ~0x1FFFull;
                    if (isq) bb2 |= code;
                    buf[vl * RS + slot] = __longlong_as_double(bb2);
                }
            __threadfence_block();    // LDS writes committed before signal
            if (l == 0) atomicAdd(&sem[step], 1);
        }
    } else {
        for (int step = 0; step < 4; ++step) {
            for (;;) {                // wait: all 8 producers packed chunk step
                int c0 = 0;
                if (l == 0) c0 = atomicAdd(&sem[step], 0);
                if (__shfl(c0, 0) >= 8) break;
                __builtin_amdgcn_s_sleep(2);
            }
            const double* row = S + (step & 1) * BUFD + (size_t)vs * 32 * RS;
            #pragma unroll 2
            for (int vi = 0; vi < 32; ++vi, row += RS) {
                vdbl4 qv = *(const vdbl4*)(row + qi * 4);
                vdbl4 kv = *(const vdbl4*)(row + 64 + kb * 4);
                #pragma unroll
                for (int a = 0; a < 4; ++a) {
                    best[a][0] = fmax(best[a][0], qv[a] + kv[0]);
                    best[a][1] = fmax(best[a][1], qv[a] + kv[1]);
                    best[a][2] = fmax(best[a][2], qv[a] + kv[2]);
                    best[a][3] = fmax(best[a][3], qv[a] + kv[3]);
                }
            }
            __threadfence_block();    // ds_reads complete before freeing buffer
            if (l == 0) atomicAdd(&sem[4 + step], 1);
        }
        // ---- cross-slice merge: wait until ALL consumer waves left the
        //      buffers (red region aliases buf0), then 2-way merge ----
        for (;;) {
            int c0 = 0;
            if (l == 0) c0 = atomicAdd(&sem[7], 0);
            if (__shfl(c0, 0) >= 8) break;
            __builtin_amdgcn_s_sleep(2);
        }
        double* red = S;              // [16 pairs][256 threads] = 32 KB
        if (vs == 0) {
            #pragma unroll
            for (int j = 0; j < 16; ++j)
                red[j * 256 + ci] = best[j >> 2][j & 3];
            __threadfence_block();
            if (l == 0) atomicAdd(&sem[8], 1);
        } else {
            for (;;) {
                int c0 = 0;
                if (l == 0) c0 = atomicAdd(&sem[8], 0);
                if (__shfl(c0, 0) >= 4) break;
                __builtin_amdgcn_s_sleep(2);
            }
            int cib = ci - 256;
            #pragma unroll
            for (int j = 0; j < 16; ++j) {
                double m = fmax(best[j >> 2][j & 3], red[j * 256 + cib]);
                int q = qi * 4 + (j >> 2);
                int k = kb * 4 + (j & 3);
                // positive doubles: bit order == numeric order; max order-independent
                atomicMax(&bestf[((size_t)bh * 64 + q) * 64 + k],
                          (unsigned long long)__double_as_longlong(m));
            }
        }
    }
}

// ======== combine (r12 exact): 1024 blocks = q(64) x bh(16) ========
__global__ __launch_bounds__(256) void k_combine(
    const unsigned long long* __restrict__ bestf,
    const double* __restrict__ qp, const double* __restrict__ kp,
    const float* __restrict__ E,
    const float* __restrict__ lng, const float* __restrict__ lnb,
    float* __restrict__ out)
{
    int bid = blockIdx.x;             // 1024 = q(64) x bh(16)
    int bh = bid & 15, q = bid >> 4;
    int b = bh >> 3, h = bh & 7;
    int t = threadIdx.x;
    int w = t >> 6, lane = t & 63;

    __shared__ double qrow[64];
    __shared__ double gpart[4][64];
    __shared__ double knpart[4][64];
    __shared__ double qnpart[4];
    __shared__ float  ws_l[64];
    __shared__ int    idx_l[64];
    __shared__ float  epart[4][64];

    if (t < 64) qrow[t] = qp[(size_t)(b * 64 + q) * INNER + h * 64 + t];
    __syncthreads();

    {
        const double* krow = kp + (size_t)(b * 64 + lane) * INNER + h * 64 + w * 16;
        double gd = 0.0, kn = 0.0;
        #pragma unroll
        for (int i = 0; i < 16; ++i) {
            double xk = krow[i];
            gd = fma(qrow[w * 16 + i], xk, gd);
            kn = fma(xk, xk, kn);
        }
        gpart[w][lane] = gd;
        knpart[w][lane] = kn;
        if (lane == 0) {
            double qn = 0.0;
            #pragma unroll
            for (int i = 0; i < 16; ++i) { double xq = qrow[w * 16 + i]; qn = fma(xq, xq, qn); }
            qnpart[w] = qn;
        }
    }
    __syncthreads();

    if (w == 0) {
        int k = lane;
        double gdot = (gpart[0][k] + gpart[1][k]) + (gpart[2][k] + gpart[3][k]);
        double kn2  = (knpart[0][k] + knpart[1][k]) + (knpart[2][k] + knpart[3][k]);
        double qn2  = (qnpart[0] + qnpart[1]) + (qnpart[2] + qnpart[3]);
        unsigned long long bb = bestf[((size_t)bh * 64 + q) * 64 + k];
        int vidx = 4095 - (int)(bb & 0xFFFull);
        double sval = __longlong_as_double(bb & ~0x1FFFull);
        double tru = (sval - 3.0) * 64.0;
        double n2 = qn2 + kn2 + 2.0 * gdot;
        double wsim = tru * (1.0 / sqrt(fmax(n2, 1e-12)));
        size_t oidx = ((size_t)(b * QLEN + q) * KLEN + k) * NH + h;
        out[65536 + oidx] = (float)vidx;          // out_ids as float32
        out[131072 + oidx] = (float)wsim;         // r3_scores
        ws_l[k] = (float)wsim;
        idx_l[k] = vidx;
    }
    __syncthreads();

    {
        int d = lane;
        float acc = 0.0f;
        #pragma unroll 4
        for (int k2 = w * 16; k2 < w * 16 + 16; ++k2)
            acc += E[idx_l[k2] * DKV + d] * ws_l[k2];
        epart[w][d] = acc;
    }
    __syncthreads();

    if (w == 0) {
        int d = lane;
        float acc = ((epart[0][d] + epart[1][d]) + (epart[2][d] + epart[3][d])) * (1.0f / 64.0f);
        float mean = acc;
        for (int m = 32; m >= 1; m >>= 1) mean += __shfl_xor(mean, m);
        mean *= (1.0f / 64.0f);
        float dv = acc - mean;
        float var = dv * dv;
        for (int m = 32; m >= 1; m >>= 1) var += __shfl_xor(var, m);
        var *= (1.0f / 64.0f);
        float o = dv * rsqrtf(var + 1e-6f) * lng[d] + lnb[d];
        out[(((size_t)b * NH + h) * QLEN + q) * DKV + d] = o;
    }
}

extern "C" void kernel_launch(void* const* d_in, const int* in_sizes, int n_in,
                              void* d_out, int out_size, void* d_ws, size_t ws_size,
                              hipStream_t stream) {
    const float* query = (const float*)d_in[0];
    const float* key   = (const float*)d_in[1];
    const float* qpe   = (const float*)d_in[2];
    const float* kpe   = (const float*)d_in[3];
    const float* wi    = (const float*)d_in[4];
    const float* vq    = (const float*)d_in[5];
    const float* vqg   = (const float*)d_in[6];
    const float* vqb   = (const float*)d_in[7];
    const float* ow    = (const float*)d_in[8];
    const float* lng   = (const float*)d_in[9];
    const float* lnb   = (const float*)d_in[10];
    float* out = (float*)d_out;

    char* ws = (char*)d_ws;
    double* qp  = (double*)(ws + 0);
    double* kp  = (double*)(ws + 524288);
    double* dnt = (double*)(ws + 1048576);
    float*  E   = (float*) (ws + 3145728);
    unsigned long long* bestf = (unsigned long long*)(ws + 4194304);

    k_prep   <<<2048, 256, 0, stream>>>(query, key, qpe, kpe, wi, vq, vqg, vqb, ow,
                                        qp, kp, dnt, E, bestf);
    k_simscan<<<256, 1024, 0, stream>>>(qp, kp, dnt, bestf);
    k_combine<<<1024, 256, 0, stream>>>(bestf, qp, kp, E, lng, lnb, out);
}

// Round 5
// 153.354 us; speedup vs baseline: 1.0997x; 1.0924x over previous
//
#include <hip/hip_runtime.h>
#include <math.h>

#define BS 2
#define QLEN 64
#define KLEN 64
#define NH 8
#define DKV 64
#define INNER 512
#define VOCAB 4096
#define CHUNKV 64
#define RS 130               // Cv stride (doubles), even -> 16B-aligned b128 reads
#define BUFD (CHUNKV * RS)   // 8320 doubles per buffer

typedef double vdbl4 __attribute__((ext_vector_type(4)));
typedef double vdbl2 __attribute__((ext_vector_type(2)));

// ---------------- workspace layout (bytes) ----------------
// qp    : [BS][64][INNER] double  @ 0        (512 KB)
// kp    : [BS][64][INNER] double  @ 512 KB   (512 KB)
// dnt   : [DKV][VOCAB]    double  @ 1 MB     (2 MB)   l2-normalized dict, transposed
// E     : [VOCAB][DKV]    float   @ 3 MB     (1 MB)   LN(dict) @ vq_o_w
// bestf : [16][64][64]    u64     @ 4 MB     (512 KB) atomicMax'd packed (val | 4095-v code)

// ======== prep: proj GEMM (blocks 0..1023) + dict (blocks 1024..2047) — r12 exact ========
__global__ __launch_bounds__(256) void k_prep(
    const float* __restrict__ q_in, const float* __restrict__ k_in,
    const float* __restrict__ qpe, const float* __restrict__ kpe,
    const float* __restrict__ wi,
    const float* __restrict__ vq, const float* __restrict__ g,
    const float* __restrict__ bta, const float* __restrict__ ow,
    double* __restrict__ qp, double* __restrict__ kp,
    double* __restrict__ dnt, float* __restrict__ E,
    unsigned long long* __restrict__ bestf)
{
    __shared__ double S[1600];           // proj: xs[1024]+red[512]; dict: Lsh[256]+Dsh[320]
    __shared__ float Osh[4096];          // dict: ow cache
    int bid = blockIdx.x;
    int t = threadIdx.x;

    if (bid < 1024) {
        int side = bid >> 9;
        int b    = (bid >> 8) & 1;
        int rp   = (bid >> 3) & 31;
        int cb   = bid & 7;
        const float* xin = side ? k_in : q_in;
        const float* pin = side ? kpe : qpe;
        double* outp = side ? kp : qp;
        int wrow0 = side ? INNER : 0;
        int r0 = rp * 2;
        double* xs = S;                  // [2][512]
        double* red = S + 1024;          // [dh*2+rr][64]
        for (int i = t; i < 2 * INNER; i += 256) {
            int rr = i >> 9, dd = i & 511;
            int gidx = (b * 64 + r0 + rr) * INNER + dd;
            xs[rr * INNER + dd] = (double)xin[gidx] + (double)pin[gidx];
        }
        __syncthreads();
        int col = cb * 64 + (t & 63);
        int dh = t >> 6;
        double a0 = 0.0, a1 = 0.0;
        #pragma unroll 8
        for (int d = dh * 128; d < dh * 128 + 128; ++d) {
            double w = (double)wi[(size_t)(wrow0 + d) * INNER + col];
            a0 = fma(xs[d], w, a0);
            a1 = fma(xs[INNER + d], w, a1);
        }
        red[(dh * 2 + 0) * 64 + (t & 63)] = a0;
        red[(dh * 2 + 1) * 64 + (t & 63)] = a1;
        __syncthreads();
        if (t < 128) {
            int rr = t >> 6, c2 = t & 63;
            double s = (red[(0 * 2 + rr) * 64 + c2] + red[(1 * 2 + rr) * 64 + c2])
                     + (red[(2 * 2 + rr) * 64 + c2] + red[(3 * 2 + rr) * 64 + c2]);
            outp[(size_t)(b * 64 + r0 + rr) * INNER + cb * 64 + c2] = s;
        }
    } else {
        int db = bid - 1024;             // 0..1023, 4 vocab rows each (1 per wave)
        if (db < 256) bestf[db * 256 + t] = 0ull;
        double* Lsh = S;                 // [wave(4)][64] LN values
        double* Dsh = S + 256;           // [j(64)][5] dn staging (vloc = wave)
        int vb = db * 4;
        int wv = t >> 6, lane = t & 63;
        for (int i = t; i < 4096; i += 256) Osh[i] = ow[i];
        int v = vb + wv;
        double z = (double)vq[v * DKV + lane];
        double s2 = z * z, s1 = z;
        for (int m = 32; m >= 1; m >>= 1) { s2 += __shfl_xor(s2, m); s1 += __shfl_xor(s1, m); }
        Dsh[lane * 5 + wv] = z * (1.0 / sqrt(fmax(s2, 1e-12)));
        double mean = s1 * (1.0 / 64.0);
        double d0 = z - mean;
        double vv2 = d0 * d0;
        for (int m = 32; m >= 1; m >>= 1) vv2 += __shfl_xor(vv2, m);
        vv2 *= (1.0 / 64.0);
        Lsh[wv * 64 + lane] = d0 * (1.0 / sqrt(vv2 + 1e-6)) * (double)g[lane] + (double)bta[lane];
        __syncthreads();
        double c0 = 0.0, c1 = 0.0, c2 = 0.0, c3 = 0.0;
        #pragma unroll 4
        for (int gg = 0; gg < 16; ++gg) {
            int jj = gg * 4;
            c0 = fma(Lsh[wv * 64 + jj + 0], (double)Osh[(jj + 0) * 64 + lane], c0);
            c1 = fma(Lsh[wv * 64 + jj + 1], (double)Osh[(jj + 1) * 64 + lane], c1);
            c2 = fma(Lsh[wv * 64 + jj + 2], (double)Osh[(jj + 2) * 64 + lane], c2);
            c3 = fma(Lsh[wv * 64 + jj + 3], (double)Osh[(jj + 3) * 64 + lane], c3);
        }
        E[v * DKV + lane] = (float)((c0 + c1) + (c2 + c3));
        {
            int j = t >> 2, vloc = t & 3;
            dnt[(size_t)j * VOCAB + vb + vloc] = Dsh[j * 5 + vloc];
        }
    }
}

// ======== producer/consumer MFMA-f64 sim + scan — LDS-semaphore sync ========
// r0-proven structure (61us): producers signal prod_cnt[s] after packing chunk
// s; consumers spin, scan, signal cons_cnt[s]; producer of step s waits on
// cons_cnt[s-2] (2-buffer reuse). No s_barrier in the loop. Consumer: 4q x 2k
// tile per thread (16 VGPR state -- fits the empirical 64-arch-VGPR budget of
// 16-wave MFMA blocks; r1-r4 showed bigger tiles/merge stages cost +15us).
// r5 micro-trim: the two vdbl2 q-reads at consecutive slots 4qg..4qg+3 are a
// single aligned vdbl4 (same addresses, one fewer LDS issue per v).
__global__ __launch_bounds__(1024, 4) void k_simscan(
    const double* __restrict__ qp, const double* __restrict__ kp,
    const double* __restrict__ dnt,
    unsigned long long* __restrict__ bestf)
{
    int bid = blockIdx.x;             // 256 = cg(16) x bh(16)
    int bh = bid & 15, cg = bid >> 4;
    int b = bh >> 3, h = bh & 7;
    int t = threadIdx.x;
    int w = t >> 6, l = t & 63;

    __shared__ double S[2 * BUFD];    // 133120 B -> 1 block/CU
    __shared__ int sem[8];            // [0..3]=prod_cnt, [4..7]=cons_cnt

    int asub = l >> 4;
    int lrow = l & 15;
    bool isprod = (w < 8);

    if (t < 8) sem[t] = 0;

    // ---- D-layout probes (verified calibration, rounds 6-15) ----
    int drow[4], dcol[4];
    {
        vdbl4 prow = (vdbl4){0.0, 0.0, 0.0, 0.0};
        vdbl4 pcol = (vdbl4){0.0, 0.0, 0.0, 0.0};
        double a_row = (asub == 0) ? (double)lrow : 0.0;
        double b_one = (asub == 0) ? 1.0 : 0.0;
        double a_one = (asub == 0) ? 1.0 : 0.0;
        double b_col = (asub == 0) ? (double)lrow : 0.0;
        prow = __builtin_amdgcn_mfma_f64_16x16x4f64(a_row, b_one, prow, 0, 0, 0);
        pcol = __builtin_amdgcn_mfma_f64_16x16x4f64(a_one, b_col, pcol, 0, 0, 0);
        #pragma unroll
        for (int r = 0; r < 4; ++r) { drow[r] = (int)prow[r]; dcol[r] = (int)pcol[r]; }
    }

    // ---- producer state: A-frags for 1 row-tile x 16 ksteps (loaded once) ----
    double afr[16];
    if (isprod) {
        const double* src = (w < 4) ? qp : kp;
        int arow = (w & 3) * 16 + lrow;
        #pragma unroll
        for (int ks = 0; ks < 16; ++ks)
            afr[ks] = src[(size_t)(b * 64 + arow) * INNER + h * 64 + ks * 4 + asub];
    }

    // ---- consumer state (waves 8-15): 8 pairs q in {qg+16i}, k in {kg+32j} ----
    int ci = t - 512;
    int qg = ci & 15, kg = (ci >> 4) & 31;
    double best[4][2];
    #pragma unroll
    for (int i = 0; i < 4; ++i)
        #pragma unroll
        for (int j = 0; j < 2; ++j) best[i][j] = 0.0;

    __syncthreads();                  // sem init visible to all (only barrier)

    if (isprod) {
        for (int step = 0; step < 4; ++step) {
            if (step >= 2) {          // wait: consumers done with buf[step&1]
                for (;;) {
                    int c0 = 0;
                    if (l == 0) c0 = atomicAdd(&sem[4 + step - 2], 0);
                    if (__shfl(c0, 0) >= 8) break;
                    __builtin_amdgcn_s_sleep(2);
                }
            }
            int v0 = (cg * 4 + step) * CHUNKV;
            double* buf = S + (step & 1) * BUFD;
            vdbl4 acc[4];
            #pragma unroll
            for (int vt = 0; vt < 4; ++vt) acc[vt] = (vdbl4){0.0, 0.0, 0.0, 0.0};
            size_t base = (size_t)asub * VOCAB + v0 + lrow;
            double bcur[4], bnext[4];
            #pragma unroll
            for (int vt = 0; vt < 4; ++vt) bcur[vt] = dnt[base + vt * 16];
            #pragma unroll
            for (int ks = 0; ks < 16; ++ks) {
                if (ks < 15) {
                    size_t krow = base + (size_t)((ks + 1) * 4) * VOCAB;
                    #pragma unroll
                    for (int vt = 0; vt < 4; ++vt) bnext[vt] = dnt[krow + vt * 16];
                }
                #pragma unroll
                for (int vt = 0; vt < 4; ++vt)
                    acc[vt] = __builtin_amdgcn_mfma_f64_16x16x4f64(
                        afr[ks], bcur[vt], acc[vt], 0, 0, 0);
                if (ks < 15) {
                    #pragma unroll
                    for (int vt = 0; vt < 4; ++vt) bcur[vt] = bnext[vt];
                }
            }
            // pack: affine to [1.25,1.75], clear low 13 bits, embed (4095-v)<<1 on q
            // side; store at PERMUTED slot so consumer reads are contiguous b128.
            bool isq = (w < 4);
            #pragma unroll
            for (int vt = 0; vt < 4; ++vt)
                #pragma unroll
                for (int r = 0; r < 4; ++r) {
                    int vl = vt * 16 + dcol[r];
                    int grow = (w & 3) * 16 + drow[r];     // global row 0..63 within side
                    int slot = isq ? ((grow & 15) * 4 + (grow >> 4))
                                   : (64 + (grow & 31) * 2 + (grow >> 5));
                    unsigned long long code =
                        (unsigned long long)((4095 - (v0 + vl)) << 1);
                    double s = fma(acc[vt][r], 1.0 / 64.0, 1.5);
                    unsigned long long bb2 = __double_as_longlong(s) & ~0x1FFFull;
                    if (isq) bb2 |= code;
                    buf[vl * RS + slot] = __longlong_as_double(bb2);
                }
            __threadfence_block();    // LDS writes committed before signal
            if (l == 0) atomicAdd(&sem[step], 1);
        }
    } else {
        for (int step = 0; step < 4; ++step) {
            for (;;) {                // wait: all 8 producers packed chunk step
                int c0 = 0;
                if (l == 0) c0 = atomicAdd(&sem[step], 0);
                if (__shfl(c0, 0) >= 8) break;
                __builtin_amdgcn_s_sleep(2);
            }
            double* buf = S + (step & 1) * BUFD;
            #pragma unroll 2
            for (int v = 0; v < CHUNKV; ++v) {
                vdbl4 qv = *(const vdbl4*)&buf[v * RS + qg * 4];        // q = qg,+16,+32,+48
                vdbl2 k01 = *(const vdbl2*)&buf[v * RS + 64 + kg * 2];  // k = kg, kg+32
                best[0][0] = fmax(best[0][0], qv[0] + k01[0]);
                best[0][1] = fmax(best[0][1], qv[0] + k01[1]);
                best[1][0] = fmax(best[1][0], qv[1] + k01[0]);
                best[1][1] = fmax(best[1][1], qv[1] + k01[1]);
                best[2][0] = fmax(best[2][0], qv[2] + k01[0]);
                best[2][1] = fmax(best[2][1], qv[2] + k01[1]);
                best[3][0] = fmax(best[3][0], qv[3] + k01[0]);
                best[3][1] = fmax(best[3][1], qv[3] + k01[1]);
            }
            __threadfence_block();    // ds_reads complete before freeing buffer
            if (l == 0) atomicAdd(&sem[4 + step], 1);
        }
        #pragma unroll
        for (int i = 0; i < 4; ++i)
            #pragma unroll
            for (int j = 0; j < 2; ++j) {
                int q = qg + 16 * i, k = kg + 32 * j;
                // positive doubles: bit order == numeric order; max order-independent
                atomicMax(&bestf[((size_t)bh * 64 + q) * 64 + k],
                          (unsigned long long)__double_as_longlong(best[i][j]));
            }
    }
}

// ======== combine (r12 exact): 1024 blocks = q(64) x bh(16) ========
__global__ __launch_bounds__(256) void k_combine(
    const unsigned long long* __restrict__ bestf,
    const double* __restrict__ qp, const double* __restrict__ kp,
    const float* __restrict__ E,
    const float* __restrict__ lng, const float* __restrict__ lnb,
    float* __restrict__ out)
{
    int bid = blockIdx.x;             // 1024 = q(64) x bh(16)
    int bh = bid & 15, q = bid >> 4;
    int b = bh >> 3, h = bh & 7;
    int t = threadIdx.x;
    int w = t >> 6, lane = t & 63;

    __shared__ double qrow[64];
    __shared__ double gpart[4][64];
    __shared__ double knpart[4][64];
    __shared__ double qnpart[4];
    __shared__ float  ws_l[64];
    __shared__ int    idx_l[64];
    __shared__ float  epart[4][64];

    if (t < 64) qrow[t] = qp[(size_t)(b * 64 + q) * INNER + h * 64 + t];
    __syncthreads();

    {
        const double* krow = kp + (size_t)(b * 64 + lane) * INNER + h * 64 + w * 16;
        double gd = 0.0, kn = 0.0;
        #pragma unroll
        for (int i = 0; i < 16; ++i) {
            double xk = krow[i];
            gd = fma(qrow[w * 16 + i], xk, gd);
            kn = fma(xk, xk, kn);
        }
        gpart[w][lane] = gd;
        knpart[w][lane] = kn;
        if (lane == 0) {
            double qn = 0.0;
            #pragma unroll
            for (int i = 0; i < 16; ++i) { double xq = qrow[w * 16 + i]; qn = fma(xq, xq, qn); }
            qnpart[w] = qn;
        }
    }
    __syncthreads();

    if (w == 0) {
        int k = lane;
        double gdot = (gpart[0][k] + gpart[1][k]) + (gpart[2][k] + gpart[3][k]);
        double kn2  = (knpart[0][k] + knpart[1][k]) + (knpart[2][k] + knpart[3][k]);
        double qn2  = (qnpart[0] + qnpart[1]) + (qnpart[2] + qnpart[3]);
        unsigned long long bb = bestf[((size_t)bh * 64 + q) * 64 + k];
        int vidx = 4095 - (int)(bb & 0xFFFull);
        double sval = __longlong_as_double(bb & ~0x1FFFull);
        double tru = (sval - 3.0) * 64.0;
        double n2 = qn2 + kn2 + 2.0 * gdot;
        double wsim = tru * (1.0 / sqrt(fmax(n2, 1e-12)));
        size_t oidx = ((size_t)(b * QLEN + q) * KLEN + k) * NH + h;
        out[65536 + oidx] = (float)vidx;          // out_ids as float32
        out[131072 + oidx] = (float)wsim;         // r3_scores
        ws_l[k] = (float)wsim;
        idx_l[k] = vidx;
    }
    __syncthreads();

    {
        int d = lane;
        float acc = 0.0f;
        #pragma unroll 4
        for (int k2 = w * 16; k2 < w * 16 + 16; ++k2)
            acc += E[idx_l[k2] * DKV + d] * ws_l[k2];
        epart[w][d] = acc;
    }
    __syncthreads();

    if (w == 0) {
        int d = lane;
        float acc = ((epart[0][d] + epart[1][d]) + (epart[2][d] + epart[3][d])) * (1.0f / 64.0f);
        float mean = acc;
        for (int m = 32; m >= 1; m >>= 1) mean += __shfl_xor(mean, m);
        mean *= (1.0f / 64.0f);
        float dv = acc - mean;
        float var = dv * dv;
        for (int m = 32; m >= 1; m >>= 1) var += __shfl_xor(var, m);
        var *= (1.0f / 64.0f);
        float o = dv * rsqrtf(var + 1e-6f) * lng[d] + lnb[d];
        out[(((size_t)b * NH + h) * QLEN + q) * DKV + d] = o;
    }
}

extern "C" void kernel_launch(void* const* d_in, const int* in_sizes, int n_in,
                              void* d_out, int out_size, void* d_ws, size_t ws_size,
                              hipStream_t stream) {
    const float* query = (const float*)d_in[0];
    const float* key   = (const float*)d_in[1];
    const float* qpe   = (const float*)d_in[2];
    const float* kpe   = (const float*)d_in[3];
    const float* wi    = (const float*)d_in[4];
    const float* vq    = (const float*)d_in[5];
    const float* vqg   = (const float*)d_in[6];
    const float* vqb   = (const float*)d_in[7];
    const float* ow    = (const float*)d_in[8];
    const float* lng   = (const float*)d_in[9];
    const float* lnb   = (const float*)d_in[10];
    float* out = (float*)d_out;

    char* ws = (char*)d_ws;
    double* qp  = (double*)(ws + 0);
    double* kp  = (double*)(ws + 524288);
    double* dnt = (double*)(ws + 1048576);
    float*  E   = (float*) (ws + 3145728);
    unsigned long long* bestf = (unsigned long long*)(ws + 4194304);

    k_prep   <<<2048, 256, 0, stream>>>(query, key, qpe, kpe, wi, vq, vqg, vqb, ow,
                                        qp, kp, dnt, E, bestf);
    k_simscan<<<256, 1024, 0, stream>>>(qp, kp, dnt, bestf);
    k_combine<<<1024, 256, 0, stream>>>(bestf, qp, kp, E, lng, lnb, out);
}

// Round 7
// 151.422 us; speedup vs baseline: 1.1138x; 1.0128x over previous
//
#include <hip/hip_runtime.h>
#include <math.h>

#define BS 2
#define QLEN 64
#define KLEN 64
#define NH 8
#define DKV 64
#define INNER 512
#define VOCAB 4096
#define CHUNKV 64
#define RS 130               // Cv stride (doubles), even -> 16B-aligned b128 reads
#define BUFD (CHUNKV * RS)   // 8320 doubles per buffer

typedef double vdbl4 __attribute__((ext_vector_type(4)));
typedef double vdbl2 __attribute__((ext_vector_type(2)));

// ---------------- workspace layout (bytes) ----------------
// qp    : [BS][64][INNER] double  @ 0        (512 KB)
// kp    : [BS][64][INNER] double  @ 512 KB   (512 KB)
// dnt   : [DKV][VOCAB]    double  @ 1 MB     (2 MB)   l2-normalized dict, transposed
// E     : [VOCAB][DKV]    float   @ 3 MB     (1 MB)   LN(dict) @ vq_o_w
// bestf : [16][64][64]    u64     @ 4 MB     (512 KB) atomicMax'd packed (val | 4095-v code)

// ======== prep: proj GEMM (blocks 0..1023) + dict (blocks 1024..2047) — r12 exact ========
__global__ __launch_bounds__(256) void k_prep(
    const float* __restrict__ q_in, const float* __restrict__ k_in,
    const float* __restrict__ qpe, const float* __restrict__ kpe,
    const float* __restrict__ wi,
    const float* __restrict__ vq, const float* __restrict__ g,
    const float* __restrict__ bta, const float* __restrict__ ow,
    double* __restrict__ qp, double* __restrict__ kp,
    double* __restrict__ dnt, float* __restrict__ E,
    unsigned long long* __restrict__ bestf)
{
    __shared__ double S[1600];           // proj: xs[1024]+red[512]; dict: Lsh[256]+Dsh[320]
    __shared__ float Osh[4096];          // dict: ow cache
    int bid = blockIdx.x;
    int t = threadIdx.x;

    if (bid < 1024) {
        int side = bid >> 9;
        int b    = (bid >> 8) & 1;
        int rp   = (bid >> 3) & 31;
        int cb   = bid & 7;
        const float* xin = side ? k_in : q_in;
        const float* pin = side ? kpe : qpe;
        double* outp = side ? kp : qp;
        int wrow0 = side ? INNER : 0;
        int r0 = rp * 2;
        double* xs = S;                  // [2][512]
        double* red = S + 1024;          // [dh*2+rr][64]
        for (int i = t; i < 2 * INNER; i += 256) {
            int rr = i >> 9, dd = i & 511;
            int gidx = (b * 64 + r0 + rr) * INNER + dd;
            xs[rr * INNER + dd] = (double)xin[gidx] + (double)pin[gidx];
        }
        __syncthreads();
        int col = cb * 64 + (t & 63);
        int dh = t >> 6;
        double a0 = 0.0, a1 = 0.0;
        #pragma unroll 8
        for (int d = dh * 128; d < dh * 128 + 128; ++d) {
            double w = (double)wi[(size_t)(wrow0 + d) * INNER + col];
            a0 = fma(xs[d], w, a0);
            a1 = fma(xs[INNER + d], w, a1);
        }
        red[(dh * 2 + 0) * 64 + (t & 63)] = a0;
        red[(dh * 2 + 1) * 64 + (t & 63)] = a1;
        __syncthreads();
        if (t < 128) {
            int rr = t >> 6, c2 = t & 63;
            double s = (red[(0 * 2 + rr) * 64 + c2] + red[(1 * 2 + rr) * 64 + c2])
                     + (red[(2 * 2 + rr) * 64 + c2] + red[(3 * 2 + rr) * 64 + c2]);
            outp[(size_t)(b * 64 + r0 + rr) * INNER + cb * 64 + c2] = s;
        }
    } else {
        int db = bid - 1024;             // 0..1023, 4 vocab rows each (1 per wave)
        if (db < 256) bestf[db * 256 + t] = 0ull;
        double* Lsh = S;                 // [wave(4)][64] LN values
        double* Dsh = S + 256;           // [j(64)][5] dn staging (vloc = wave)
        int vb = db * 4;
        int wv = t >> 6, lane = t & 63;
        for (int i = t; i < 4096; i += 256) Osh[i] = ow[i];
        int v = vb + wv;
        double z = (double)vq[v * DKV + lane];
        double s2 = z * z, s1 = z;
        for (int m = 32; m >= 1; m >>= 1) { s2 += __shfl_xor(s2, m); s1 += __shfl_xor(s1, m); }
        Dsh[lane * 5 + wv] = z * (1.0 / sqrt(fmax(s2, 1e-12)));
        double mean = s1 * (1.0 / 64.0);
        double d0 = z - mean;
        double vv2 = d0 * d0;
        for (int m = 32; m >= 1; m >>= 1) vv2 += __shfl_xor(vv2, m);
        vv2 *= (1.0 / 64.0);
        Lsh[wv * 64 + lane] = d0 * (1.0 / sqrt(vv2 + 1e-6)) * (double)g[lane] + (double)bta[lane];
        __syncthreads();
        double c0 = 0.0, c1 = 0.0, c2 = 0.0, c3 = 0.0;
        #pragma unroll 4
        for (int gg = 0; gg < 16; ++gg) {
            int jj = gg * 4;
            c0 = fma(Lsh[wv * 64 + jj + 0], (double)Osh[(jj + 0) * 64 + lane], c0);
            c1 = fma(Lsh[wv * 64 + jj + 1], (double)Osh[(jj + 1) * 64 + lane], c1);
            c2 = fma(Lsh[wv * 64 + jj + 2], (double)Osh[(jj + 2) * 64 + lane], c2);
            c3 = fma(Lsh[wv * 64 + jj + 3], (double)Osh[(jj + 3) * 64 + lane], c3);
        }
        E[v * DKV + lane] = (float)((c0 + c1) + (c2 + c3));
        {
            int j = t >> 2, vloc = t & 3;
            dnt[(size_t)j * VOCAB + vb + vloc] = Dsh[j * 5 + vloc];
        }
    }
}

// ======== producer/consumer MFMA-f64 sim + scan — LDS-semaphore sync ========
// r0-proven structure (61us), unchanged since r5.
__global__ __launch_bounds__(1024, 4) void k_simscan(
    const double* __restrict__ qp, const double* __restrict__ kp,
    const double* __restrict__ dnt,
    unsigned long long* __restrict__ bestf)
{
    int bid = blockIdx.x;             // 256 = cg(16) x bh(16)
    int bh = bid & 15, cg = bid >> 4;
    int b = bh >> 3, h = bh & 7;
    int t = threadIdx.x;
    int w = t >> 6, l = t & 63;

    __shared__ double S[2 * BUFD];    // 133120 B -> 1 block/CU
    __shared__ int sem[8];            // [0..3]=prod_cnt, [4..7]=cons_cnt

    int asub = l >> 4;
    int lrow = l & 15;
    bool isprod = (w < 8);

    if (t < 8) sem[t] = 0;

    // ---- D-layout probes (verified calibration, rounds 6-15) ----
    int drow[4], dcol[4];
    {
        vdbl4 prow = (vdbl4){0.0, 0.0, 0.0, 0.0};
        vdbl4 pcol = (vdbl4){0.0, 0.0, 0.0, 0.0};
        double a_row = (asub == 0) ? (double)lrow : 0.0;
        double b_one = (asub == 0) ? 1.0 : 0.0;
        double a_one = (asub == 0) ? 1.0 : 0.0;
        double b_col = (asub == 0) ? (double)lrow : 0.0;
        prow = __builtin_amdgcn_mfma_f64_16x16x4f64(a_row, b_one, prow, 0, 0, 0);
        pcol = __builtin_amdgcn_mfma_f64_16x16x4f64(a_one, b_col, pcol, 0, 0, 0);
        #pragma unroll
        for (int r = 0; r < 4; ++r) { drow[r] = (int)prow[r]; dcol[r] = (int)pcol[r]; }
    }

    // ---- producer state: A-frags for 1 row-tile x 16 ksteps (loaded once) ----
    double afr[16];
    if (isprod) {
        const double* src = (w < 4) ? qp : kp;
        int arow = (w & 3) * 16 + lrow;
        #pragma unroll
        for (int ks = 0; ks < 16; ++ks)
            afr[ks] = src[(size_t)(b * 64 + arow) * INNER + h * 64 + ks * 4 + asub];
    }

    // ---- consumer state (waves 8-15): 8 pairs q in {qg+16i}, k in {kg+32j} ----
    int ci = t - 512;
    int qg = ci & 15, kg = (ci >> 4) & 31;
    double best[4][2];
    #pragma unroll
    for (int i = 0; i < 4; ++i)
        #pragma unroll
        for (int j = 0; j < 2; ++j) best[i][j] = 0.0;

    __syncthreads();                  // sem init visible to all (only barrier)

    if (isprod) {
        for (int step = 0; step < 4; ++step) {
            if (step >= 2) {          // wait: consumers done with buf[step&1]
                for (;;) {
                    int c0 = 0;
                    if (l == 0) c0 = atomicAdd(&sem[4 + step - 2], 0);
                    if (__shfl(c0, 0) >= 8) break;
                    __builtin_amdgcn_s_sleep(2);
                }
            }
            int v0 = (cg * 4 + step) * CHUNKV;
            double* buf = S + (step & 1) * BUFD;
            vdbl4 acc[4];
            #pragma unroll
            for (int vt = 0; vt < 4; ++vt) acc[vt] = (vdbl4){0.0, 0.0, 0.0, 0.0};
            size_t base = (size_t)asub * VOCAB + v0 + lrow;
            double bcur[4], bnext[4];
            #pragma unroll
            for (int vt = 0; vt < 4; ++vt) bcur[vt] = dnt[base + vt * 16];
            #pragma unroll
            for (int ks = 0; ks < 16; ++ks) {
                if (ks < 15) {
                    size_t krow = base + (size_t)((ks + 1) * 4) * VOCAB;
                    #pragma unroll
                    for (int vt = 0; vt < 4; ++vt) bnext[vt] = dnt[krow + vt * 16];
                }
                #pragma unroll
                for (int vt = 0; vt < 4; ++vt)
                    acc[vt] = __builtin_amdgcn_mfma_f64_16x16x4f64(
                        afr[ks], bcur[vt], acc[vt], 0, 0, 0);
                if (ks < 15) {
                    #pragma unroll
                    for (int vt = 0; vt < 4; ++vt) bcur[vt] = bnext[vt];
                }
            }
            // pack: affine to [1.25,1.75], clear low 13 bits, embed (4095-v)<<1 on q
            // side; store at PERMUTED slot so consumer reads are contiguous b128.
            bool isq = (w < 4);
            #pragma unroll
            for (int vt = 0; vt < 4; ++vt)
                #pragma unroll
                for (int r = 0; r < 4; ++r) {
                    int vl = vt * 16 + dcol[r];
                    int grow = (w & 3) * 16 + drow[r];     // global row 0..63 within side
                    int slot = isq ? ((grow & 15) * 4 + (grow >> 4))
                                   : (64 + (grow & 31) * 2 + (grow >> 5));
                    unsigned long long code =
                        (unsigned long long)((4095 - (v0 + vl)) << 1);
                    double s = fma(acc[vt][r], 1.0 / 64.0, 1.5);
                    unsigned long long bb2 = __double_as_longlong(s) & ~0x1FFFull;
                    if (isq) bb2 |= code;
                    buf[vl * RS + slot] = __longlong_as_double(bb2);
                }
            __threadfence_block();    // LDS writes committed before signal
            if (l == 0) atomicAdd(&sem[step], 1);
        }
    } else {
        for (int step = 0; step < 4; ++step) {
            for (;;) {                // wait: all 8 producers packed chunk step
                int c0 = 0;
                if (l == 0) c0 = atomicAdd(&sem[step], 0);
                if (__shfl(c0, 0) >= 8) break;
                __builtin_amdgcn_s_sleep(2);
            }
            double* buf = S + (step & 1) * BUFD;
            #pragma unroll 2
            for (int v = 0; v < CHUNKV; ++v) {
                vdbl4 qv = *(const vdbl4*)&buf[v * RS + qg * 4];        // q = qg,+16,+32,+48
                vdbl2 k01 = *(const vdbl2*)&buf[v * RS + 64 + kg * 2];  // k = kg, kg+32
                best[0][0] = fmax(best[0][0], qv[0] + k01[0]);
                best[0][1] = fmax(best[0][1], qv[0] + k01[1]);
                best[1][0] = fmax(best[1][0], qv[1] + k01[0]);
                best[1][1] = fmax(best[1][1], qv[1] + k01[1]);
                best[2][0] = fmax(best[2][0], qv[2] + k01[0]);
                best[2][1] = fmax(best[2][1], qv[2] + k01[1]);
                best[3][0] = fmax(best[3][0], qv[3] + k01[0]);
                best[3][1] = fmax(best[3][1], qv[3] + k01[1]);
            }
            __threadfence_block();    // ds_reads complete before freeing buffer
            if (l == 0) atomicAdd(&sem[4 + step], 1);
        }
        #pragma unroll
        for (int i = 0; i < 4; ++i)
            #pragma unroll
            for (int j = 0; j < 2; ++j) {
                int q = qg + 16 * i, k = kg + 32 * j;
                // positive doubles: bit order == numeric order; max order-independent
                atomicMax(&bestf[((size_t)bh * 64 + q) * 64 + k],
                          (unsigned long long)__double_as_longlong(best[i][j]));
            }
    }
}

// ======== combine: 1024 blocks = q(64) x bh(16) ========
// r6: the kp read was 64-way UNCOALESCED (lane stride 4KB: each wave-load
// touched 64 cache lines -> ~1GB of L2 transactions across the dispatch,
// est. 30-40us). Fix: stage the block's [64k][64d] kp slice into LDS with
// lane->d coalesced loads (one 512B txn per wave-instr), store TRANSPOSED
// kt[d][k] with pad-65 (write ~4-way conflict, tiny pass; read kt[i][lane]
// lane-consecutive -> conflict-free). Compute loop now reads LDS.
__global__ __launch_bounds__(256) void k_combine(
    const unsigned long long* __restrict__ bestf,
    const double* __restrict__ qp, const double* __restrict__ kp,
    const float* __restrict__ E,
    const float* __restrict__ lng, const float* __restrict__ lnb,
    float* __restrict__ out)
{
    int bid = blockIdx.x;             // 1024 = q(64) x bh(16)
    int bh = bid & 15, q = bid >> 4;
    int b = bh >> 3, h = bh & 7;
    int t = threadIdx.x;
    int w = t >> 6, lane = t & 63;

    __shared__ double qrow[64];
    __shared__ double kt[64][65];     // [d][k], pad 65
    __shared__ double gpart[4][64];
    __shared__ double knpart[4][64];
    __shared__ double qnpart[4];
    __shared__ float  ws_l[64];
    __shared__ int    idx_l[64];
    __shared__ float  epart[4][64];

    if (t < 64) qrow[t] = qp[(size_t)(b * 64 + q) * INNER + h * 64 + t];
    // coalesced kp stage: per wave-instr k is uniform, d=lane -> 512B txn
    #pragma unroll
    for (int j = 0; j < 16; ++j) {
        int k = j * 4 + w;            // 0..63
        kt[lane][k] = kp[(size_t)(b * 64 + k) * INNER + h * 64 + lane];
    }
    __syncthreads();

    {
        double gd = 0.0, kn = 0.0;
        #pragma unroll
        for (int i = 0; i < 16; ++i) {
            double xk = kt[w * 16 + i][lane];          // lane=k, conflict-free
            gd = fma(qrow[w * 16 + i], xk, gd);
            kn = fma(xk, xk, kn);
        }
        gpart[w][lane] = gd;
        knpart[w][lane] = kn;
        if (lane == 0) {
            double qn = 0.0;
            #pragma unroll
            for (int i = 0; i < 16; ++i) { double xq = qrow[w * 16 + i]; qn = fma(xq, xq, qn); }
            qnpart[w] = qn;
        }
    }
    __syncthreads();

    if (w == 0) {
        int k = lane;
        double gdot = (gpart[0][k] + gpart[1][k]) + (gpart[2][k] + gpart[3][k]);
        double kn2  = (knpart[0][k] + knpart[1][k]) + (knpart[2][k] + knpart[3][k]);
        double qn2  = (qnpart[0] + qnpart[1]) + (qnpart[2] + qnpart[3]);
        unsigned long long bb = bestf[((size_t)bh * 64 + q) * 64 + k];
        int vidx = 4095 - (int)(bb & 0xFFFull);
        double sval = __longlong_as_double(bb & ~0x1FFFull);
        double tru = (sval - 3.0) * 64.0;
        double n2 = qn2 + kn2 + 2.0 * gdot;
        double wsim = tru * (1.0 / sqrt(fmax(n2, 1e-12)));
        size_t oidx = ((size_t)(b * QLEN + q) * KLEN + k) * NH + h;
        out[65536 + oidx] = (float)vidx;          // out_ids as float32
        out[131072 + oidx] = (float)wsim;         // r3_scores
        ws_l[k] = (float)wsim;
        idx_l[k] = vidx;
    }
    __syncthreads();

    {
        int d = lane;
        float acc = 0.0f;
        #pragma unroll 4
        for (int k2 = w * 16; k2 < w * 16 + 16; ++k2)
            acc += E[idx_l[k2] * DKV + d] * ws_l[k2];
        epart[w][d] = acc;
    }
    __syncthreads();

    if (w == 0) {
        int d = lane;
        float acc = ((epart[0][d] + epart[1][d]) + (epart[2][d] + epart[3][d])) * (1.0f / 64.0f);
        float mean = acc;
        for (int m = 32; m >= 1; m >>= 1) mean += __shfl_xor(mean, m);
        mean *= (1.0f / 64.0f);
        float dv = acc - mean;
        float var = dv * dv;
        for (int m = 32; m >= 1; m >>= 1) var += __shfl_xor(var, m);
        var *= (1.0f / 64.0f);
        float o = dv * rsqrtf(var + 1e-6f) * lng[d] + lnb[d];
        out[(((size_t)b * NH + h) * QLEN + q) * DKV + d] = o;
    }
}

extern "C" void kernel_launch(void* const* d_in, const int* in_sizes, int n_in,
                              void* d_out, int out_size, void* d_ws, size_t ws_size,
                              hipStream_t stream) {
    const float* query = (const float*)d_in[0];
    const float* key   = (const float*)d_in[1];
    const float* qpe   = (const float*)d_in[2];
    const float* kpe   = (const float*)d_in[3];
    const float* wi    = (const float*)d_in[4];
    const float* vq    = (const float*)d_in[5];
    const float* vqg   = (const float*)d_in[6];
    const float* vqb   = (const float*)d_in[7];
    const float* ow    = (const float*)d_in[8];
    const float* lng   = (const float*)d_in[9];
    const float* lnb   = (const float*)d_in[10];
    float* out = (float*)d_out;

    char* ws = (char*)d_ws;
    double* qp  = (double*)(ws + 0);
    double* kp  = (double*)(ws + 524288);
    double* dnt = (double*)(ws + 1048576);
    float*  E   = (float*) (ws + 3145728);
    unsigned long long* bestf = (unsigned long long*)(ws + 4194304);

    k_prep   <<<2048, 256, 0, stream>>>(query, key, qpe, kpe, wi, vq, vqg, vqb, ow,
                                        qp, kp, dnt, E, bestf);
    k_simscan<<<256, 1024, 0, stream>>>(qp, kp, dnt, bestf);
    k_combine<<<1024, 256, 0, stream>>>(bestf, qp, kp, E, lng, lnb, out);
}